// Round 6
// baseline (2117.673 us; speedup 1.0000x reference)
//
#include <hip/hip_runtime.h>
#include <hip/hip_bf16.h>

#define HH 128
#define WW 128

typedef _Float16 half4_t __attribute__((ext_vector_type(4)));
typedef _Float16 half8 __attribute__((ext_vector_type(8)));
typedef float f32x4 __attribute__((ext_vector_type(4)));

// ---------------------------------------------------------------------------
// Weight transform: fp32 [oc][ic][3][3] -> f16 [tap][oc][ic] per layer.
// Layers 0..15 rb_w1, 16..31 rb_w2, 32 body (OC=64), 33 super (OC padded 448).
// ---------------------------------------------------------------------------
__global__ __launch_bounds__(256)
void wxform_k(const float* __restrict__ rb_w1, const float* __restrict__ rb_w2,
              const float* __restrict__ body_w, const float* __restrict__ super_w,
              _Float16* __restrict__ Wt) {
    const int per64 = 64 * 64 * 9;          // 36864
    const int n64   = 33 * per64;           // 1216512
    const int total = n64 + 448 * 64 * 9;   // + 258048
    for (int i = blockIdx.x * 256 + threadIdx.x; i < total; i += gridDim.x * 256) {
        if (i < n64) {
            int l  = i / per64;
            int r  = i - l * per64;
            int ic = r & 63, oc = (r >> 6) & 63, tap = r >> 12;
            const float* src = (l < 16) ? (rb_w1 + (size_t)l * per64)
                             : (l < 32) ? (rb_w2 + (size_t)(l - 16) * per64)
                                        : body_w;
            Wt[i] = (_Float16)src[(oc * 64 + ic) * 9 + tap];
        } else {
            int r   = i - n64;
            int ic  = r & 63;
            int oc  = (r >> 6) % 448;
            int tap = (r >> 6) / 448;
            float v = (oc < 400) ? super_w[((size_t)oc * 64 + ic) * 9 + tap] : 0.f;
            Wt[i] = (_Float16)v;
        }
    }
}

// ---------------------------------------------------------------------------
// Head conv: 3 -> 64, fused mean subtraction. Output f16 4c layout.
// ---------------------------------------------------------------------------
__global__ __launch_bounds__(256)
void head_k(const float* __restrict__ x, const float* __restrict__ w,
            const float* __restrict__ b, _Float16* __restrict__ out) {
    int n  = blockIdx.z;
    int gx = blockIdx.x * 16 + (threadIdx.x & 15);
    int gy = blockIdx.y * 16 + (threadIdx.x >> 4);
    float msub[3] = {255.0f * 0.4488f, 255.0f * 0.4371f, 255.0f * 0.4040f};
    float iv[27];
#pragma unroll
    for (int c = 0; c < 3; ++c)
#pragma unroll
        for (int dy = 0; dy < 3; ++dy)
#pragma unroll
            for (int dx = 0; dx < 3; ++dx) {
                int yy = gy + dy - 1, xx = gx + dx - 1;
                float v = 0.f;
                if ((unsigned)yy < HH && (unsigned)xx < WW)
                    v = x[(((size_t)n * 3 + c) * HH + yy) * WW + xx] - msub[c];
                iv[c * 9 + dy * 3 + dx] = v;
            }
    for (int ocg = 0; ocg < 16; ++ocg) {
        half4_t o;
#pragma unroll
        for (int q = 0; q < 4; ++q) {
            int oc  = ocg * 4 + q;
            float a = b[oc];
#pragma unroll
            for (int t = 0; t < 27; ++t) a = fmaf(iv[t], w[oc * 27 + t], a);
            o[q] = (_Float16)a;
        }
        *(half4_t*)&out[((((size_t)n * 16 + ocg) * HH + gy) * WW + gx) * 4] = o;
    }
}

// ---------------------------------------------------------------------------
// Fused resblock: out = in + conv2(relu(conv1(in))). Tile: 16x8 conv2-out px.
// r6: NO input LDS stage -- conv1 B-frags load directly from global (2x8B,
// bounds-predicated; halo dups hit L1/L2). Only sMid (conv1 out, halo +-1,
// 23 KB) lives in LDS -> ~3 blocks/CU. One barrier per block.
// conv1: 4 waves = 2 row-chunks x 2 overlapping px-16 tiles. conv2: 4 waves
// = 2 row-groups x 2 oc-halves. Residual read from global (L2-warm).
// conv1 halo outputs OUTSIDE the image are stored as ZERO in sMid.
// ---------------------------------------------------------------------------
__global__ __launch_bounds__(256, 3)
void frb_k(const _Float16* __restrict__ in, const _Float16* __restrict__ W1,
           const _Float16* __restrict__ W2, const float* __restrict__ b1,
           const float* __restrict__ b2, _Float16* __restrict__ out) {
    __shared__ __align__(16) _Float16 sMid[10 * 18 * 64];  // 23.0 KB

    int tid = threadIdx.x;
    int n = blockIdx.z, bx = blockIdx.x, by = blockIdx.y;
    int wv = tid >> 6, lane = tid & 63;
    int lx = lane & 15, lg = lane >> 4;

    // ---- conv1: rows c0..c0+4 (c0 = -1 or 4), px p0+lx (p0 = -1 or 1) ----
    {
        int c0 = -1 + (wv >> 1) * 5;
        int p0 = -1 + (wv & 1) * 2;
        f32x4 acc[5][4];
#pragma unroll
        for (int r = 0; r < 5; ++r)
#pragma unroll
            for (int t = 0; t < 4; ++t) acc[r][t] = (f32x4){0.f, 0.f, 0.f, 0.f};

#pragma unroll
        for (int icstep = 0; icstep < 2; ++icstep) {
            int icoff = icstep * 32 + lg * 8;
            int icg2  = (icstep * 4 + lg) * 2;   // first 4c plane of the 8-ic granule
#pragma unroll
            for (int dx = 0; dx < 3; ++dx) {
                int gx  = bx * 16 + p0 + lx + dx - 1;
                bool cok = (unsigned)gx < (unsigned)WW;
                half8 Bf[7];
#pragma unroll
                for (int d = 0; d < 7; ++d) {
                    int gy  = by * 8 + c0 + d - 1;
                    bool ok = cok && ((unsigned)gy < (unsigned)HH);
                    size_t base = ((((size_t)n * 16 + icg2) * HH + gy) * WW + gx) * 4;
                    half4_t a = ok ? *(const half4_t*)&in[base] : (half4_t){0, 0, 0, 0};
                    half4_t c = ok ? *(const half4_t*)&in[base + (size_t)HH * WW * 4]
                                   : (half4_t){0, 0, 0, 0};
                    half8 v;
                    v[0] = a[0]; v[1] = a[1]; v[2] = a[2]; v[3] = a[3];
                    v[4] = c[0]; v[5] = c[1]; v[6] = c[2]; v[7] = c[3];
                    Bf[d] = v;
                }
#pragma unroll
                for (int dy = 0; dy < 3; ++dy) {
                    int tap = dy * 3 + dx;
                    half8 Af[4];
#pragma unroll
                    for (int t = 0; t < 4; ++t)
                        Af[t] = *(const half8*)&W1[((size_t)(tap * 64 + t * 16 + lx)) * 64 + icoff];
#pragma unroll
                    for (int r = 0; r < 5; ++r)
#pragma unroll
                        for (int t = 0; t < 4; ++t)
                            acc[r][t] = __builtin_amdgcn_mfma_f32_16x16x32_f16(
                                Af[t], Bf[r + dy], acc[r][t], 0, 0, 0);
                }
            }
        }
        // epilogue -> sMid (bias + relu, f16); zero if outside image
        int gcol = bx * 16 + p0 + lx;
        bool colok = (unsigned)gcol < (unsigned)WW;
#pragma unroll
        for (int r = 0; r < 5; ++r) {
            int row  = c0 + r + 1;                    // sMid row 0..9
            int grow = by * 8 + c0 + r;               // global conv1-out row
            bool ok  = colok && ((unsigned)grow < (unsigned)HH);
#pragma unroll
            for (int t = 0; t < 4; ++t) {
                int oc0 = t * 16 + lg * 4;
                f32x4 bv = *(const f32x4*)&b1[oc0];
                int pl2 = row * 18 + (p0 + lx + 1);
                half4_t o;
#pragma unroll
                for (int q = 0; q < 4; ++q)
                    o[q] = ok ? (_Float16)fmaxf(acc[r][t][q] + bv[q], 0.f)
                              : (_Float16)0.f;
                *(half4_t*)&sMid[pl2 * 64 + (((oc0 >> 3) ^ (pl2 & 7)) << 3) + (oc0 & 4)] = o;
            }
        }
    }
    __syncthreads();

    // ---- conv2: rows r0..r0+3 (r0 = 0 or 4), oc-half h (32 oc) ----
    {
        int r0 = (wv & 1) * 4;
        int h  = wv >> 1;
        f32x4 acc[4][2];
#pragma unroll
        for (int r = 0; r < 4; ++r)
#pragma unroll
            for (int t = 0; t < 2; ++t) acc[r][t] = (f32x4){0.f, 0.f, 0.f, 0.f};

#pragma unroll
        for (int icstep = 0; icstep < 2; ++icstep) {
            int icoff = icstep * 32 + lg * 8;
            int icg   = icoff >> 3;
#pragma unroll
            for (int dx = 0; dx < 3; ++dx) {
                half8 Bf[6];
#pragma unroll
                for (int d = 0; d < 6; ++d) {
                    int pl = (r0 + d) * 18 + lx + dx;
                    Bf[d] = *(const half8*)&sMid[pl * 64 + ((icg ^ (pl & 7)) << 3)];
                }
#pragma unroll
                for (int dy = 0; dy < 3; ++dy) {
                    int tap = dy * 3 + dx;
                    half8 Af[2];
#pragma unroll
                    for (int t = 0; t < 2; ++t)
                        Af[t] = *(const half8*)&W2[((size_t)(tap * 64 + h * 32 + t * 16 + lx)) * 64 + icoff];
#pragma unroll
                    for (int r = 0; r < 4; ++r)
#pragma unroll
                        for (int t = 0; t < 2; ++t)
                            acc[r][t] = __builtin_amdgcn_mfma_f32_16x16x32_f16(
                                Af[t], Bf[r + dy], acc[r][t], 0, 0, 0);
                }
            }
        }
        // epilogue: + bias + residual (global), store global f16 4c
        int gx0 = bx * 16 + lx;
#pragma unroll
        for (int r = 0; r < 4; ++r) {
            int y = by * 8 + r0 + r;
#pragma unroll
            for (int t = 0; t < 2; ++t) {
                int oc0 = h * 32 + t * 16 + lg * 4;
                f32x4 bv = *(const f32x4*)&b2[oc0];
                size_t gi = ((((size_t)n * 16 + (oc0 >> 2)) * HH + y) * WW + gx0) * 4;
                half4_t rs = *(const half4_t*)&in[gi];
                half4_t o;
#pragma unroll
                for (int q = 0; q < 4; ++q)
                    o[q] = (_Float16)(acc[r][t][q] + bv[q] + (float)rs[q]);
                *(half4_t*)&out[gi] = o;
            }
        }
    }
}

// ---------------------------------------------------------------------------
// MFMA conv, IC=64, 512 threads / 8 waves. Tile 16x8 px (23 KB LDS -> 4
// blocks/CU); waves = 4 row-groups(2 rows) x 2 oc-halves looping oc by 64.
// NT: nontemporal output stores (bypass L2 -> protect weight lines).
// ---------------------------------------------------------------------------
template<bool RES, bool NT>
__global__ __launch_bounds__(512)
void mconv_k(const _Float16* __restrict__ in, const _Float16* __restrict__ Wt,
             const float* __restrict__ bias, const _Float16* __restrict__ resid,
             _Float16* __restrict__ out, int OCp, int OCr, int C4) {
    __shared__ __align__(16) _Float16 sIn[10 * 18 * 64];  // 23 KB

    int tid = threadIdx.x;
    int n = blockIdx.z, bx = blockIdx.x, by = blockIdx.y;

    for (int i = tid; i < 1440; i += 512) {
        int icg = i / 180, pl = i - icg * 180;
        int py = pl / 18, px = pl - py * 18;
        int gy = by * 8 + py - 1, gx = bx * 16 + px - 1;
        half8 v = {0, 0, 0, 0, 0, 0, 0, 0};
        if ((unsigned)gy < (unsigned)HH && (unsigned)gx < (unsigned)WW) {
            size_t base = ((((size_t)n * 16 + icg * 2) * HH + gy) * WW + gx) * 4;
            half4_t a = *(const half4_t*)&in[base];
            half4_t c = *(const half4_t*)&in[base + (size_t)HH * WW * 4];
            v[0] = a[0]; v[1] = a[1]; v[2] = a[2]; v[3] = a[3];
            v[4] = c[0]; v[5] = c[1]; v[6] = c[2]; v[7] = c[3];
        }
        *(half8*)&sIn[pl * 64 + ((icg ^ (pl & 7)) << 3)] = v;
    }
    __syncthreads();

    int wv = tid >> 6, lane = tid & 63;
    int lx = lane & 15, lg = lane >> 4;
    int r0 = (wv & 3) * 2;
    int h  = wv >> 2;
    int gx0 = bx * 16 + lx;

    for (int ocb = h * 32; ocb < OCp; ocb += 64) {
        f32x4 acc[2][2];
#pragma unroll
        for (int r = 0; r < 2; ++r)
#pragma unroll
            for (int t = 0; t < 2; ++t) acc[r][t] = (f32x4){0.f, 0.f, 0.f, 0.f};

#pragma unroll
        for (int icstep = 0; icstep < 2; ++icstep) {
            int icoff = icstep * 32 + lg * 8;
            int icg   = icoff >> 3;
#pragma unroll
            for (int dx = 0; dx < 3; ++dx) {
                half8 Bf[4];
#pragma unroll
                for (int d = 0; d < 4; ++d) {
                    int pl = (r0 + d) * 18 + lx + dx;
                    Bf[d] = *(const half8*)&sIn[pl * 64 + ((icg ^ (pl & 7)) << 3)];
                }
#pragma unroll
                for (int dy = 0; dy < 3; ++dy) {
                    int tap = dy * 3 + dx;
                    half8 Af[2];
#pragma unroll
                    for (int t = 0; t < 2; ++t)
                        Af[t] = *(const half8*)&Wt[((size_t)(tap * OCp + ocb + t * 16 + lx)) * 64 + icoff];
#pragma unroll
                    for (int r = 0; r < 2; ++r)
#pragma unroll
                        for (int t = 0; t < 2; ++t)
                            acc[r][t] = __builtin_amdgcn_mfma_f32_16x16x32_f16(
                                Af[t], Bf[r + dy], acc[r][t], 0, 0, 0);
                }
            }
        }
#pragma unroll
        for (int r = 0; r < 2; ++r) {
            int y = by * 8 + r0 + r;
#pragma unroll
            for (int t = 0; t < 2; ++t) {
                int oc0 = ocb + t * 16 + lg * 4;
                if (oc0 >= OCr) continue;
                f32x4 bv = *(const f32x4*)&bias[oc0];
                size_t gi = ((((size_t)n * C4 + (oc0 >> 2)) * HH + y) * WW + gx0) * 4;
                float vv[4];
#pragma unroll
                for (int q = 0; q < 4; ++q) vv[q] = acc[r][t][q] + bv[q];
                if (RES) {
                    half4_t rg = *(const half4_t*)&resid[gi];
#pragma unroll
                    for (int q = 0; q < 4; ++q) vv[q] += (float)rg[q];
                }
                half4_t o;
#pragma unroll
                for (int q = 0; q < 4; ++q) o[q] = (_Float16)vv[q];
                if (NT) __builtin_nontemporal_store(o, (half4_t*)&out[gi]);
                else    *(half4_t*)&out[gi] = o;
            }
        }
    }
}

// ---------------------------------------------------------------------------
// Out conv 100->3 at 256x256 over pixel-shuffled super output (f16 4c; the
// 4c granule IS the 4 shuffle phases). Thread = 2x2 output quad. Mean add.
// ---------------------------------------------------------------------------
__global__ __launch_bounds__(256)
void out_k(const _Float16* __restrict__ S, const float* __restrict__ w,
           const float* __restrict__ b, float* __restrict__ out) {
    int n = blockIdx.z;
    int a  = blockIdx.y * 16 + (threadIdx.x >> 4);
    int bc = blockIdx.x * 16 + (threadIdx.x & 15);
    float acc[3][2][2];
#pragma unroll
    for (int c = 0; c < 3; ++c)
#pragma unroll
        for (int oy = 0; oy < 2; ++oy)
#pragma unroll
            for (int ox = 0; ox < 2; ++ox) acc[c][oy][ox] = 0.f;

    for (int ic = 0; ic < 100; ++ic) {
        float g[3][3][4];
#pragma unroll
        for (int yi = 0; yi < 3; ++yi) {
            int Y = a - 1 + yi;
#pragma unroll
            for (int xi = 0; xi < 3; ++xi) {
                int X = bc - 1 + xi;
                half4_t hv = {0, 0, 0, 0};
                if ((unsigned)Y < 128u && (unsigned)X < 128u)
                    hv = *(const half4_t*)&S[((((size_t)n * 100 + ic) * 128 + Y) * 128 + X) * 4];
#pragma unroll
                for (int s = 0; s < 4; ++s) g[yi][xi][s] = (float)hv[s];
            }
        }
#pragma unroll
        for (int oy = 0; oy < 2; ++oy)
#pragma unroll
            for (int ox = 0; ox < 2; ++ox)
#pragma unroll
                for (int dy = 0; dy < 3; ++dy)
#pragma unroll
                    for (int dx = 0; dx < 3; ++dx) {
                        const int ey = oy + dy - 1, ex = ox + dx - 1;
                        const int yi = (ey >> 1) + 1, xi = (ex >> 1) + 1;
                        const int sub = (ey & 1) * 2 + (ex & 1);
                        float v = g[yi][xi][sub];
#pragma unroll
                        for (int c = 0; c < 3; ++c)
                            acc[c][oy][ox] = fmaf(v, w[(c * 100 + ic) * 9 + dy * 3 + dx],
                                                  acc[c][oy][ox]);
                    }
    }
    const float madd[3] = {255.0f * 0.4488f, 255.0f * 0.4371f, 255.0f * 0.4040f};
#pragma unroll
    for (int c = 0; c < 3; ++c)
#pragma unroll
        for (int oy = 0; oy < 2; ++oy)
#pragma unroll
            for (int ox = 0; ox < 2; ++ox)
                out[(((size_t)n * 3 + c) * 256 + 2 * a + oy) * 256 + 2 * bc + ox] =
                    acc[c][oy][ox] + b[c] + madd[c];
}

// ---------------------------------------------------------------------------
extern "C" void kernel_launch(void* const* d_in, const int* in_sizes, int n_in,
                              void* d_out, int out_size, void* d_ws, size_t ws_size,
                              hipStream_t stream) {
    const float* x       = (const float*)d_in[0];
    const float* head_w  = (const float*)d_in[1];
    const float* head_b  = (const float*)d_in[2];
    const float* rb_w1   = (const float*)d_in[3];
    const float* rb_b1   = (const float*)d_in[4];
    const float* rb_w2   = (const float*)d_in[5];
    const float* rb_b2   = (const float*)d_in[6];
    const float* body_w  = (const float*)d_in[7];
    const float* body_b  = (const float*)d_in[8];
    const float* super_w = (const float*)d_in[9];
    const float* super_b = (const float*)d_in[10];
    const float* out_w   = (const float*)d_in[11];
    const float* out_b   = (const float*)d_in[12];
    float* out = (float*)d_out;

    const size_t ACT = (size_t)16777216;  // bytes per f16 activation buffer
    char* wsb = (char*)d_ws;
    _Float16* Tb = (_Float16*)wsb;                      // ping / body-out / super-in
    _Float16* Hb = (_Float16*)(wsb + ACT);              // head out (kept for body skip)
    _Float16* Cb = (_Float16*)(wsb + 2 * ACT);          // pong
    _Float16* Sb = (_Float16*)(wsb + ACT);              // super out (Hb/Cb dead then)
    _Float16* Wt = (_Float16*)(wsb + ACT + 104857600);

    // 0) weight transform
    wxform_k<<<dim3(1440), 256, 0, stream>>>(rb_w1, rb_w2, body_w, super_w, Wt);

    // 1) head
    head_k<<<dim3(8, 8, 8), 256, 0, stream>>>(x, head_w, head_b, Hb);

    const _Float16* Wt_bod = Wt + (size_t)32 * 36864;
    const _Float16* Wt_sup = Wt + (size_t)33 * 36864;

    // 2) fused resblocks (ping-pong Tb/Cb; Hb preserved)
    const _Float16* cur = Hb;
    for (int i = 0; i < 16; ++i) {
        _Float16* dst = (i & 1) ? Cb : Tb;
        frb_k<<<dim3(8, 16, 8), 256, 0, stream>>>(
            cur, Wt + (size_t)i * 36864, Wt + (size_t)(16 + i) * 36864,
            rb_b1 + i * 64, rb_b2 + i * 64, dst);
        cur = dst;
    }
    // cur == Cb after rb15
    // 3) body conv + head skip -> Tb
    mconv_k<true, false><<<dim3(8, 16, 8), 512, 0, stream>>>(
        Cb, Wt_bod, body_b, Hb, Tb, 64, 64, 16);
    // 4) super conv 64->400 (padded 448) -> Sb, nontemporal stores
    mconv_k<false, true><<<dim3(8, 16, 8), 512, 0, stream>>>(
        Tb, Wt_sup, super_b, nullptr, Sb, 448, 400, 100);
    // 5) out conv over pixel-shuffled granules + mean add
    out_k<<<dim3(8, 8, 8), 256, 0, stream>>>(Sb, out_w, out_b, out);
}

// Round 7
// 1829.930 us; speedup vs baseline: 1.1572x; 1.1572x over previous
//
#include <hip/hip_runtime.h>
#include <hip/hip_bf16.h>

#define HH 128
#define WW 128

typedef _Float16 half4_t __attribute__((ext_vector_type(4)));
typedef _Float16 half8 __attribute__((ext_vector_type(8)));
typedef float f32x4 __attribute__((ext_vector_type(4)));

// ---------------------------------------------------------------------------
// Weight transform: fp32 [oc][ic][3][3] -> f16 [tap][oc][ic] per layer.
// Layers 0..15 rb_w1, 16..31 rb_w2, 32 body (OC=64), 33 super (OC padded 448).
// ---------------------------------------------------------------------------
__global__ __launch_bounds__(256)
void wxform_k(const float* __restrict__ rb_w1, const float* __restrict__ rb_w2,
              const float* __restrict__ body_w, const float* __restrict__ super_w,
              _Float16* __restrict__ Wt) {
    const int per64 = 64 * 64 * 9;          // 36864
    const int n64   = 33 * per64;           // 1216512
    const int total = n64 + 448 * 64 * 9;   // + 258048
    for (int i = blockIdx.x * 256 + threadIdx.x; i < total; i += gridDim.x * 256) {
        if (i < n64) {
            int l  = i / per64;
            int r  = i - l * per64;
            int ic = r & 63, oc = (r >> 6) & 63, tap = r >> 12;
            const float* src = (l < 16) ? (rb_w1 + (size_t)l * per64)
                             : (l < 32) ? (rb_w2 + (size_t)(l - 16) * per64)
                                        : body_w;
            Wt[i] = (_Float16)src[(oc * 64 + ic) * 9 + tap];
        } else {
            int r   = i - n64;
            int ic  = r & 63;
            int oc  = (r >> 6) % 448;
            int tap = (r >> 6) / 448;
            float v = (oc < 400) ? super_w[((size_t)oc * 64 + ic) * 9 + tap] : 0.f;
            Wt[i] = (_Float16)v;
        }
    }
}

// ---------------------------------------------------------------------------
// Head conv: 3 -> 64, fused mean subtraction. Output f16 4c layout.
// ---------------------------------------------------------------------------
__global__ __launch_bounds__(256)
void head_k(const float* __restrict__ x, const float* __restrict__ w,
            const float* __restrict__ b, _Float16* __restrict__ out) {
    int n  = blockIdx.z;
    int gx = blockIdx.x * 16 + (threadIdx.x & 15);
    int gy = blockIdx.y * 16 + (threadIdx.x >> 4);
    float msub[3] = {255.0f * 0.4488f, 255.0f * 0.4371f, 255.0f * 0.4040f};
    float iv[27];
#pragma unroll
    for (int c = 0; c < 3; ++c)
#pragma unroll
        for (int dy = 0; dy < 3; ++dy)
#pragma unroll
            for (int dx = 0; dx < 3; ++dx) {
                int yy = gy + dy - 1, xx = gx + dx - 1;
                float v = 0.f;
                if ((unsigned)yy < HH && (unsigned)xx < WW)
                    v = x[(((size_t)n * 3 + c) * HH + yy) * WW + xx] - msub[c];
                iv[c * 9 + dy * 3 + dx] = v;
            }
    for (int ocg = 0; ocg < 16; ++ocg) {
        half4_t o;
#pragma unroll
        for (int q = 0; q < 4; ++q) {
            int oc  = ocg * 4 + q;
            float a = b[oc];
#pragma unroll
            for (int t = 0; t < 27; ++t) a = fmaf(iv[t], w[oc * 27 + t], a);
            o[q] = (_Float16)a;
        }
        *(half4_t*)&out[((((size_t)n * 16 + ocg) * HH + gy) * WW + gx) * 4] = o;
    }
}

// ---------------------------------------------------------------------------
// Fused resblock: out = in + conv2(relu(conv1(in))). Tile: 16x8 conv2-out px.
// r7: sMid ALIASES sIn's LDS (conv1 accs live in regs across the barrier) ->
// 30.7 KB total -> 3 blocks/CU (was 53.8 KB -> 2). Residual read from global.
// conv1: 4 waves = 2 row-chunks x 2 overlapping px-16 tiles (dup writes are
// bit-identical). conv2: 4 waves = 2 row-groups x 2 oc-halves.
// conv1 halo outputs OUTSIDE the image are stored as ZERO in sMid.
// ---------------------------------------------------------------------------
__global__ __launch_bounds__(256, 3)
void frb_k(const _Float16* __restrict__ in, const _Float16* __restrict__ W1,
           const _Float16* __restrict__ W2, const float* __restrict__ b1,
           const float* __restrict__ b2, _Float16* __restrict__ out) {
    __shared__ __align__(16) _Float16 sBuf[12 * 20 * 64];  // 30.7 KB
    _Float16* sIn  = sBuf;          // 12x20x64 during staging+conv1
    _Float16* sMid = sBuf;          // 10x18x64 aliased after conv1 reads done

    int tid = threadIdx.x;
    int n = blockIdx.z, bx = blockIdx.x, by = blockIdx.y;

    // ---- stage input tile (f16 4c global -> swizzled [px][ic] LDS) ----
    for (int i = tid; i < 1920; i += 256) {
        int icg = i / 240, pl = i - icg * 240;
        int py = pl / 20, px = pl - py * 20;
        int gy = by * 8 + py - 2, gx = bx * 16 + px - 2;
        half8 v = {0, 0, 0, 0, 0, 0, 0, 0};
        if ((unsigned)gy < (unsigned)HH && (unsigned)gx < (unsigned)WW) {
            size_t base = ((((size_t)n * 16 + icg * 2) * HH + gy) * WW + gx) * 4;
            half4_t a = *(const half4_t*)&in[base];
            half4_t c = *(const half4_t*)&in[base + (size_t)HH * WW * 4];
            v[0] = a[0]; v[1] = a[1]; v[2] = a[2]; v[3] = a[3];
            v[4] = c[0]; v[5] = c[1]; v[6] = c[2]; v[7] = c[3];
        }
        *(half8*)&sIn[pl * 64 + ((icg ^ (pl & 7)) << 3)] = v;
    }
    __syncthreads();

    int wv = tid >> 6, lane = tid & 63;
    int lx = lane & 15, lg = lane >> 4;

    // ---- conv1 compute: rows c0..c0+4 (c0 = -1 or 4), px p0+lx ----
    int c0 = -1 + (wv >> 1) * 5;
    int p0 = -1 + (wv & 1) * 2;
    f32x4 acc1[5][4];
#pragma unroll
    for (int r = 0; r < 5; ++r)
#pragma unroll
        for (int t = 0; t < 4; ++t) acc1[r][t] = (f32x4){0.f, 0.f, 0.f, 0.f};

#pragma unroll
    for (int icstep = 0; icstep < 2; ++icstep) {
        int icoff = icstep * 32 + lg * 8;
        int icg   = icoff >> 3;
#pragma unroll
        for (int dx = 0; dx < 3; ++dx) {
            half8 Bf[7];
#pragma unroll
            for (int d = 0; d < 7; ++d) {
                int pl = (c0 + d + 1) * 20 + (p0 + lx + dx + 1);
                Bf[d] = *(const half8*)&sIn[pl * 64 + ((icg ^ (pl & 7)) << 3)];
            }
#pragma unroll
            for (int dy = 0; dy < 3; ++dy) {
                int tap = dy * 3 + dx;
                half8 Af[4];
#pragma unroll
                for (int t = 0; t < 4; ++t)
                    Af[t] = *(const half8*)&W1[((size_t)(tap * 64 + t * 16 + lx)) * 64 + icoff];
#pragma unroll
                for (int r = 0; r < 5; ++r)
#pragma unroll
                    for (int t = 0; t < 4; ++t)
                        acc1[r][t] = __builtin_amdgcn_mfma_f32_16x16x32_f16(
                            Af[t], Bf[r + dy], acc1[r][t], 0, 0, 0);
            }
        }
    }
    __syncthreads();   // all conv1 reads of sIn done; sMid may now overwrite

    // ---- conv1 epilogue -> sMid (bias + relu, f16); zero outside image ----
    {
        int gcol = bx * 16 + p0 + lx;
        bool colok = (unsigned)gcol < (unsigned)WW;
#pragma unroll
        for (int r = 0; r < 5; ++r) {
            int row  = c0 + r + 1;                    // sMid row 0..9
            int grow = by * 8 + c0 + r;               // global conv1-out row
            bool ok  = colok && ((unsigned)grow < (unsigned)HH);
#pragma unroll
            for (int t = 0; t < 4; ++t) {
                int oc0 = t * 16 + lg * 4;
                f32x4 bv = *(const f32x4*)&b1[oc0];
                int pl2 = row * 18 + (p0 + lx + 1);
                half4_t o;
#pragma unroll
                for (int q = 0; q < 4; ++q)
                    o[q] = ok ? (_Float16)fmaxf(acc1[r][t][q] + bv[q], 0.f)
                              : (_Float16)0.f;
                *(half4_t*)&sMid[pl2 * 64 + (((oc0 >> 3) ^ (pl2 & 7)) << 3) + (oc0 & 4)] = o;
            }
        }
    }
    __syncthreads();

    // ---- conv2: rows r0..r0+3 (r0 = 0 or 4), oc-half h (32 oc) ----
    {
        int r0 = (wv & 1) * 4;
        int h  = wv >> 1;
        f32x4 acc[4][2];
#pragma unroll
        for (int r = 0; r < 4; ++r)
#pragma unroll
            for (int t = 0; t < 2; ++t) acc[r][t] = (f32x4){0.f, 0.f, 0.f, 0.f};

#pragma unroll
        for (int icstep = 0; icstep < 2; ++icstep) {
            int icoff = icstep * 32 + lg * 8;
            int icg   = icoff >> 3;
#pragma unroll
            for (int dx = 0; dx < 3; ++dx) {
                half8 Bf[6];
#pragma unroll
                for (int d = 0; d < 6; ++d) {
                    int pl = (r0 + d) * 18 + lx + dx;
                    Bf[d] = *(const half8*)&sMid[pl * 64 + ((icg ^ (pl & 7)) << 3)];
                }
#pragma unroll
                for (int dy = 0; dy < 3; ++dy) {
                    int tap = dy * 3 + dx;
                    half8 Af[2];
#pragma unroll
                    for (int t = 0; t < 2; ++t)
                        Af[t] = *(const half8*)&W2[((size_t)(tap * 64 + h * 32 + t * 16 + lx)) * 64 + icoff];
#pragma unroll
                    for (int r = 0; r < 4; ++r)
#pragma unroll
                        for (int t = 0; t < 2; ++t)
                            acc[r][t] = __builtin_amdgcn_mfma_f32_16x16x32_f16(
                                Af[t], Bf[r + dy], acc[r][t], 0, 0, 0);
                }
            }
        }
        // epilogue: + bias + residual (global, L2-warm), store global f16 4c
        int gx0 = bx * 16 + lx;
#pragma unroll
        for (int r = 0; r < 4; ++r) {
            int y = by * 8 + r0 + r;
#pragma unroll
            for (int t = 0; t < 2; ++t) {
                int oc0 = h * 32 + t * 16 + lg * 4;
                f32x4 bv = *(const f32x4*)&b2[oc0];
                size_t gi = ((((size_t)n * 16 + (oc0 >> 2)) * HH + y) * WW + gx0) * 4;
                half4_t rs = *(const half4_t*)&in[gi];
                half4_t o;
#pragma unroll
                for (int q = 0; q < 4; ++q)
                    o[q] = (_Float16)(acc[r][t][q] + bv[q] + (float)rs[q]);
                *(half4_t*)&out[gi] = o;
            }
        }
    }
}

// ---------------------------------------------------------------------------
// MFMA conv, IC=64, 512 threads / 8 waves, tile 16x16 px. oc-loop in chunks
// of 32 with the weight chunk STAGED IN LDS (xor-swizzled) -> A-frags come
// from LDS instead of thrashing L1/L2 (the r6 super bottleneck). Waves = 8
// row-groups of 2 rows; each wave computes 2 rows x 16 px x 32 oc.
// LDS 41.5 (input) + 36.9 (weights) = 78.4 KB -> 2 blocks/CU.
// ---------------------------------------------------------------------------
template<bool RES, bool NT>
__global__ __launch_bounds__(512, 2)
void mconv_k(const _Float16* __restrict__ in, const _Float16* __restrict__ Wt,
             const float* __restrict__ bias, const _Float16* __restrict__ resid,
             _Float16* __restrict__ out, int OCp, int OCr, int C4) {
    __shared__ __align__(16) _Float16 sIn[18 * 18 * 64];  // 41.5 KB
    __shared__ __align__(16) _Float16 sW[9 * 32 * 64];    // 36.9 KB

    int tid = threadIdx.x;
    int n = blockIdx.z, bx = blockIdx.x, by = blockIdx.y;

    // ---- stage input tile ----
    for (int i = tid; i < 2592; i += 512) {
        int icg = i / 324, pl = i - icg * 324;
        int py = pl / 18, px = pl - py * 18;
        int gy = by * 16 + py - 1, gx = bx * 16 + px - 1;
        half8 v = {0, 0, 0, 0, 0, 0, 0, 0};
        if ((unsigned)gy < (unsigned)HH && (unsigned)gx < (unsigned)WW) {
            size_t base = ((((size_t)n * 16 + icg * 2) * HH + gy) * WW + gx) * 4;
            half4_t a = *(const half4_t*)&in[base];
            half4_t c = *(const half4_t*)&in[base + (size_t)HH * WW * 4];
            v[0] = a[0]; v[1] = a[1]; v[2] = a[2]; v[3] = a[3];
            v[4] = c[0]; v[5] = c[1]; v[6] = c[2]; v[7] = c[3];
        }
        *(half8*)&sIn[pl * 64 + ((icg ^ (pl & 7)) << 3)] = v;
    }
    __syncthreads();

    int wv = tid >> 6, lane = tid & 63;
    int lx = lane & 15, lg = lane >> 4;
    int r0 = wv * 2;
    int gx0 = bx * 16 + lx;

    for (int ocb = 0; ocb < OCp; ocb += 32) {
        __syncthreads();  // previous iter's sW readers done
        // ---- stage 32-oc weight chunk: [tap][oc][ic] -> swizzled LDS ----
        for (int i = tid; i < 2304; i += 512) {
            int tap = i >> 8, oc = (i >> 3) & 31, icg = i & 7;
            half8 v = *(const half8*)&Wt[((size_t)(tap * OCp + ocb + oc)) * 64 + icg * 8];
            *(half8*)&sW[(tap * 32 + oc) * 64 + ((icg ^ (oc & 7)) << 3)] = v;
        }
        __syncthreads();

        f32x4 acc[2][2];
#pragma unroll
        for (int r = 0; r < 2; ++r)
#pragma unroll
            for (int t = 0; t < 2; ++t) acc[r][t] = (f32x4){0.f, 0.f, 0.f, 0.f};

#pragma unroll
        for (int icstep = 0; icstep < 2; ++icstep) {
            int icoff = icstep * 32 + lg * 8;
            int icg   = icoff >> 3;
#pragma unroll
            for (int dx = 0; dx < 3; ++dx) {
                half8 Bf[4];
#pragma unroll
                for (int d = 0; d < 4; ++d) {
                    int pl = (r0 + d) * 18 + lx + dx;
                    Bf[d] = *(const half8*)&sIn[pl * 64 + ((icg ^ (pl & 7)) << 3)];
                }
#pragma unroll
                for (int dy = 0; dy < 3; ++dy) {
                    int tap = dy * 3 + dx;
                    half8 Af[2];
#pragma unroll
                    for (int t = 0; t < 2; ++t) {
                        int oc = t * 16 + lx;
                        Af[t] = *(const half8*)&sW[(tap * 32 + oc) * 64 + ((icg ^ (oc & 7)) << 3)];
                    }
#pragma unroll
                    for (int r = 0; r < 2; ++r)
#pragma unroll
                        for (int t = 0; t < 2; ++t)
                            acc[r][t] = __builtin_amdgcn_mfma_f32_16x16x32_f16(
                                Af[t], Bf[r + dy], acc[r][t], 0, 0, 0);
                }
            }
        }
        // ---- epilogue ----
#pragma unroll
        for (int r = 0; r < 2; ++r) {
            int y = by * 16 + r0 + r;
#pragma unroll
            for (int t = 0; t < 2; ++t) {
                int oc0 = ocb + t * 16 + lg * 4;
                if (oc0 >= OCr) continue;
                f32x4 bv = *(const f32x4*)&bias[oc0];
                size_t gi = ((((size_t)n * C4 + (oc0 >> 2)) * HH + y) * WW + gx0) * 4;
                float vv[4];
#pragma unroll
                for (int q = 0; q < 4; ++q) vv[q] = acc[r][t][q] + bv[q];
                if (RES) {
                    half4_t rg = *(const half4_t*)&resid[gi];
#pragma unroll
                    for (int q = 0; q < 4; ++q) vv[q] += (float)rg[q];
                }
                half4_t o;
#pragma unroll
                for (int q = 0; q < 4; ++q) o[q] = (_Float16)vv[q];
                if (NT) __builtin_nontemporal_store(o, (half4_t*)&out[gi]);
                else    *(half4_t*)&out[gi] = o;
            }
        }
    }
}

// ---------------------------------------------------------------------------
// Out conv 100->3 at 256x256 over pixel-shuffled super output (f16 4c; the
// 4c granule IS the 4 shuffle phases). Thread = 2x2 output quad. Mean add.
// ---------------------------------------------------------------------------
__global__ __launch_bounds__(256)
void out_k(const _Float16* __restrict__ S, const float* __restrict__ w,
           const float* __restrict__ b, float* __restrict__ out) {
    int n = blockIdx.z;
    int a  = blockIdx.y * 16 + (threadIdx.x >> 4);
    int bc = blockIdx.x * 16 + (threadIdx.x & 15);
    float acc[3][2][2];
#pragma unroll
    for (int c = 0; c < 3; ++c)
#pragma unroll
        for (int oy = 0; oy < 2; ++oy)
#pragma unroll
            for (int ox = 0; ox < 2; ++ox) acc[c][oy][ox] = 0.f;

    for (int ic = 0; ic < 100; ++ic) {
        float g[3][3][4];
#pragma unroll
        for (int yi = 0; yi < 3; ++yi) {
            int Y = a - 1 + yi;
#pragma unroll
            for (int xi = 0; xi < 3; ++xi) {
                int X = bc - 1 + xi;
                half4_t hv = {0, 0, 0, 0};
                if ((unsigned)Y < 128u && (unsigned)X < 128u)
                    hv = *(const half4_t*)&S[((((size_t)n * 100 + ic) * 128 + Y) * 128 + X) * 4];
#pragma unroll
                for (int s = 0; s < 4; ++s) g[yi][xi][s] = (float)hv[s];
            }
        }
#pragma unroll
        for (int oy = 0; oy < 2; ++oy)
#pragma unroll
            for (int ox = 0; ox < 2; ++ox)
#pragma unroll
                for (int dy = 0; dy < 3; ++dy)
#pragma unroll
                    for (int dx = 0; dx < 3; ++dx) {
                        const int ey = oy + dy - 1, ex = ox + dx - 1;
                        const int yi = (ey >> 1) + 1, xi = (ex >> 1) + 1;
                        const int sub = (ey & 1) * 2 + (ex & 1);
                        float v = g[yi][xi][sub];
#pragma unroll
                        for (int c = 0; c < 3; ++c)
                            acc[c][oy][ox] = fmaf(v, w[(c * 100 + ic) * 9 + dy * 3 + dx],
                                                  acc[c][oy][ox]);
                    }
    }
    const float madd[3] = {255.0f * 0.4488f, 255.0f * 0.4371f, 255.0f * 0.4040f};
#pragma unroll
    for (int c = 0; c < 3; ++c)
#pragma unroll
        for (int oy = 0; oy < 2; ++oy)
#pragma unroll
            for (int ox = 0; ox < 2; ++ox)
                out[(((size_t)n * 3 + c) * 256 + 2 * a + oy) * 256 + 2 * bc + ox] =
                    acc[c][oy][ox] + b[c] + madd[c];
}

// ---------------------------------------------------------------------------
extern "C" void kernel_launch(void* const* d_in, const int* in_sizes, int n_in,
                              void* d_out, int out_size, void* d_ws, size_t ws_size,
                              hipStream_t stream) {
    const float* x       = (const float*)d_in[0];
    const float* head_w  = (const float*)d_in[1];
    const float* head_b  = (const float*)d_in[2];
    const float* rb_w1   = (const float*)d_in[3];
    const float* rb_b1   = (const float*)d_in[4];
    const float* rb_w2   = (const float*)d_in[5];
    const float* rb_b2   = (const float*)d_in[6];
    const float* body_w  = (const float*)d_in[7];
    const float* body_b  = (const float*)d_in[8];
    const float* super_w = (const float*)d_in[9];
    const float* super_b = (const float*)d_in[10];
    const float* out_w   = (const float*)d_in[11];
    const float* out_b   = (const float*)d_in[12];
    float* out = (float*)d_out;

    const size_t ACT = (size_t)16777216;  // bytes per f16 activation buffer
    char* wsb = (char*)d_ws;
    _Float16* Tb = (_Float16*)wsb;                      // ping / body-out / super-in
    _Float16* Hb = (_Float16*)(wsb + ACT);              // head out (kept for body skip)
    _Float16* Cb = (_Float16*)(wsb + 2 * ACT);          // pong
    _Float16* Sb = (_Float16*)(wsb + ACT);              // super out (Hb/Cb dead then)
    _Float16* Wt = (_Float16*)(wsb + ACT + 104857600);

    // 0) weight transform
    wxform_k<<<dim3(1440), 256, 0, stream>>>(rb_w1, rb_w2, body_w, super_w, Wt);

    // 1) head
    head_k<<<dim3(8, 8, 8), 256, 0, stream>>>(x, head_w, head_b, Hb);

    const _Float16* Wt_bod = Wt + (size_t)32 * 36864;
    const _Float16* Wt_sup = Wt + (size_t)33 * 36864;

    // 2) fused resblocks (ping-pong Tb/Cb; Hb preserved)
    const _Float16* cur = Hb;
    for (int i = 0; i < 16; ++i) {
        _Float16* dst = (i & 1) ? Cb : Tb;
        frb_k<<<dim3(8, 16, 8), 256, 0, stream>>>(
            cur, Wt + (size_t)i * 36864, Wt + (size_t)(16 + i) * 36864,
            rb_b1 + i * 64, rb_b2 + i * 64, dst);
        cur = dst;
    }
    // cur == Cb after rb15
    // 3) body conv + head skip -> Tb
    mconv_k<true, false><<<dim3(8, 8, 8), 512, 0, stream>>>(
        Cb, Wt_bod, body_b, Hb, Tb, 64, 64, 16);
    // 4) super conv 64->400 (padded 448) -> Sb, nontemporal stores
    mconv_k<false, true><<<dim3(8, 8, 8), 512, 0, stream>>>(
        Tb, Wt_sup, super_b, nullptr, Sb, 448, 400, 100);
    // 5) out conv over pixel-shuffled granules + mean add
    out_k<<<dim3(8, 8, 8), 256, 0, stream>>>(Sb, out_w, out_b, out);
}

// Round 8
// 1007.276 us; speedup vs baseline: 2.1024x; 1.8167x over previous
//
#include <hip/hip_runtime.h>
#include <hip/hip_bf16.h>

#define HH 128
#define WW 128

typedef _Float16 half4_t __attribute__((ext_vector_type(4)));
typedef _Float16 half8 __attribute__((ext_vector_type(8)));
typedef float f32x4 __attribute__((ext_vector_type(4)));

// ---------------------------------------------------------------------------
// Weight transform: fp32 [oc][ic][3][3] -> f16 [tap][oc][ic] per layer.
// Layers 0..15 rb_w1, 16..31 rb_w2, 32 body (OC=64), 33 super (OC padded 448).
// ---------------------------------------------------------------------------
__global__ __launch_bounds__(256)
void wxform_k(const float* __restrict__ rb_w1, const float* __restrict__ rb_w2,
              const float* __restrict__ body_w, const float* __restrict__ super_w,
              _Float16* __restrict__ Wt) {
    const int per64 = 64 * 64 * 9;          // 36864
    const int n64   = 33 * per64;           // 1216512
    const int total = n64 + 448 * 64 * 9;   // + 258048
    for (int i = blockIdx.x * 256 + threadIdx.x; i < total; i += gridDim.x * 256) {
        if (i < n64) {
            int l  = i / per64;
            int r  = i - l * per64;
            int ic = r & 63, oc = (r >> 6) & 63, tap = r >> 12;
            const float* src = (l < 16) ? (rb_w1 + (size_t)l * per64)
                             : (l < 32) ? (rb_w2 + (size_t)(l - 16) * per64)
                                        : body_w;
            Wt[i] = (_Float16)src[(oc * 64 + ic) * 9 + tap];
        } else {
            int r   = i - n64;
            int ic  = r & 63;
            int oc  = (r >> 6) % 448;
            int tap = (r >> 6) / 448;
            float v = (oc < 400) ? super_w[((size_t)oc * 64 + ic) * 9 + tap] : 0.f;
            Wt[i] = (_Float16)v;
        }
    }
}

// ---------------------------------------------------------------------------
// Head conv: 3 -> 64, fused mean subtraction. Output f16 4c layout.
// ---------------------------------------------------------------------------
__global__ __launch_bounds__(256)
void head_k(const float* __restrict__ x, const float* __restrict__ w,
            const float* __restrict__ b, _Float16* __restrict__ out) {
    int n  = blockIdx.z;
    int gx = blockIdx.x * 16 + (threadIdx.x & 15);
    int gy = blockIdx.y * 16 + (threadIdx.x >> 4);
    float msub[3] = {255.0f * 0.4488f, 255.0f * 0.4371f, 255.0f * 0.4040f};
    float iv[27];
#pragma unroll
    for (int c = 0; c < 3; ++c)
#pragma unroll
        for (int dy = 0; dy < 3; ++dy)
#pragma unroll
            for (int dx = 0; dx < 3; ++dx) {
                int yy = gy + dy - 1, xx = gx + dx - 1;
                float v = 0.f;
                if ((unsigned)yy < HH && (unsigned)xx < WW)
                    v = x[(((size_t)n * 3 + c) * HH + yy) * WW + xx] - msub[c];
                iv[c * 9 + dy * 3 + dx] = v;
            }
    for (int ocg = 0; ocg < 16; ++ocg) {
        half4_t o;
#pragma unroll
        for (int q = 0; q < 4; ++q) {
            int oc  = ocg * 4 + q;
            float a = b[oc];
#pragma unroll
            for (int t = 0; t < 27; ++t) a = fmaf(iv[t], w[oc * 27 + t], a);
            o[q] = (_Float16)a;
        }
        *(half4_t*)&out[((((size_t)n * 16 + ocg) * HH + gy) * WW + gx) * 4] = o;
    }
}

// ---------------------------------------------------------------------------
// Fused resblock, r8: WEIGHTS STAGED IN LDS (the r2..r7 kernels streamed the
// full 73.7 KB weight set per WAVE through L1 -> L2-latency-bound, MfmaUtil
// 3-13%). sW holds one ic-half (9 tap x 64 oc x 32 ic = 36.9 KB), restaged
// between compute phases. sMid aliases sIn (accs live in regs); residual is
// captured to regs from sIn before the overwrite. LDS 30.7+36.9 = 67.6 KB
// -> 2 blocks/CU. 8 barriers/block. Tile: 16x8 conv2-out px, 4 waves.
// conv1 halo outputs OUTSIDE the image stored as ZERO in sMid.
// ---------------------------------------------------------------------------
__global__ __launch_bounds__(256, 2)
void frb_k(const _Float16* __restrict__ in, const _Float16* __restrict__ W1,
           const _Float16* __restrict__ W2, const float* __restrict__ b1,
           const float* __restrict__ b2, _Float16* __restrict__ out) {
    __shared__ __align__(16) _Float16 sBuf[15360 + 18432];  // 30.7 + 36.9 KB
    _Float16* sIn  = sBuf;          // 12x20x64 during staging+conv1
    _Float16* sMid = sBuf;          // 10x18x64, aliased after conv1 reads done
    _Float16* sW   = sBuf + 15360;  // 9 tap x 64 oc x 32 ic (one ic-half)

    int tid = threadIdx.x;
    int n = blockIdx.z, bx = blockIdx.x, by = blockIdx.y;
    int wv = tid >> 6, lane = tid & 63;
    int lx = lane & 15, lg = lane >> 4;

    // conv1 wave geometry: rows c0..c0+4 (c0 = -1 or 4), px p0+lx (p0 = -1 or 1)
    int c0 = -1 + (wv >> 1) * 5;
    int p0 = -1 + (wv & 1) * 2;
    // conv2 wave geometry: rows r0..r0+3, oc-half hh
    int r0 = (wv & 1) * 4;
    int hh = wv >> 1;

    // ---- P0: stage sIn + sW <- W1 ic-half 0 ----
    for (int i = tid; i < 1920; i += 256) {
        int icg = i / 240, pl = i - icg * 240;
        int py = pl / 20, px = pl - py * 20;
        int gy = by * 8 + py - 2, gx = bx * 16 + px - 2;
        half8 v = {0, 0, 0, 0, 0, 0, 0, 0};
        if ((unsigned)gy < (unsigned)HH && (unsigned)gx < (unsigned)WW) {
            size_t base = ((((size_t)n * 16 + icg * 2) * HH + gy) * WW + gx) * 4;
            half4_t a = *(const half4_t*)&in[base];
            half4_t c = *(const half4_t*)&in[base + (size_t)HH * WW * 4];
            v[0] = a[0]; v[1] = a[1]; v[2] = a[2]; v[3] = a[3];
            v[4] = c[0]; v[5] = c[1]; v[6] = c[2]; v[7] = c[3];
        }
        *(half8*)&sIn[pl * 64 + ((icg ^ (pl & 7)) << 3)] = v;
    }
#define STAGE_W(Wsrc, h)                                                      \
    for (int i = tid; i < 2304; i += 256) {                                   \
        int g = i & 3, oc = (i >> 2) & 63, tap = i >> 8;                      \
        half8 v = *(const half8*)&Wsrc[(size_t)(tap * 64 + oc) * 64 + (h) * 32 + g * 8]; \
        *(half8*)&sW[(tap * 64 + oc) * 32 + ((g ^ (oc & 3)) << 3)] = v;       \
    }
    STAGE_W(W1, 0)
    __syncthreads();

    f32x4 acc1[5][4];
#pragma unroll
    for (int r = 0; r < 5; ++r)
#pragma unroll
        for (int t = 0; t < 4; ++t) acc1[r][t] = (f32x4){0.f, 0.f, 0.f, 0.f};

#define CONV1_CHUNK(h)                                                        \
    {                                                                         \
        int icg = (h) * 4 + lg;                                               \
        _Pragma("unroll")                                                     \
        for (int dx = 0; dx < 3; ++dx) {                                      \
            half8 Bf[7];                                                      \
            _Pragma("unroll")                                                 \
            for (int d = 0; d < 7; ++d) {                                     \
                int pl = (c0 + d + 1) * 20 + (p0 + lx + dx + 1);              \
                Bf[d] = *(const half8*)&sIn[pl * 64 + ((icg ^ (pl & 7)) << 3)]; \
            }                                                                 \
            _Pragma("unroll")                                                 \
            for (int dy = 0; dy < 3; ++dy) {                                  \
                int tap = dy * 3 + dx;                                        \
                half8 Af[4];                                                  \
                _Pragma("unroll")                                             \
                for (int t = 0; t < 4; ++t)                                   \
                    Af[t] = *(const half8*)&sW[(tap * 64 + t * 16 + lx) * 32 + ((lg ^ (lx & 3)) << 3)]; \
                _Pragma("unroll")                                             \
                for (int r = 0; r < 5; ++r)                                   \
                    _Pragma("unroll")                                         \
                    for (int t = 0; t < 4; ++t)                               \
                        acc1[r][t] = __builtin_amdgcn_mfma_f32_16x16x32_f16(  \
                            Af[t], Bf[r + dy], acc1[r][t], 0, 0, 0);          \
            }                                                                 \
        }                                                                     \
    }

    // ---- P1: conv1 ic-half 0 ----
    CONV1_CHUNK(0)
    __syncthreads();
    // ---- P2: restage sW <- W1 ic-half 1 ----
    STAGE_W(W1, 1)
    __syncthreads();
    // ---- P3: conv1 ic-half 1 + capture residual granules to regs ----
    CONV1_CHUNK(1)
    half4_t rs[4][2];
#pragma unroll
    for (int r = 0; r < 4; ++r)
#pragma unroll
        for (int t = 0; t < 2; ++t) {
            int oc0 = hh * 32 + t * 16 + lg * 4;
            int pl  = (r0 + r + 2) * 20 + lx + 2;
            rs[r][t] = *(const half4_t*)&sIn[pl * 64 + (((oc0 >> 3) ^ (pl & 7)) << 3) + (oc0 & 4)];
        }
    __syncthreads();

    // ---- P4: conv1 epilogue -> sMid (over sIn) + stage sW <- W2 half 0 ----
    {
        int gcol = bx * 16 + p0 + lx;
        bool colok = (unsigned)gcol < (unsigned)WW;
#pragma unroll
        for (int r = 0; r < 5; ++r) {
            int row  = c0 + r + 1;                    // sMid row 0..9
            int grow = by * 8 + c0 + r;               // global conv1-out row
            bool ok  = colok && ((unsigned)grow < (unsigned)HH);
#pragma unroll
            for (int t = 0; t < 4; ++t) {
                int oc0 = t * 16 + lg * 4;
                f32x4 bv = *(const f32x4*)&b1[oc0];
                int pl2 = row * 18 + (p0 + lx + 1);
                half4_t o;
#pragma unroll
                for (int q = 0; q < 4; ++q)
                    o[q] = ok ? (_Float16)fmaxf(acc1[r][t][q] + bv[q], 0.f)
                              : (_Float16)0.f;
                *(half4_t*)&sMid[pl2 * 64 + (((oc0 >> 3) ^ (pl2 & 7)) << 3) + (oc0 & 4)] = o;
            }
        }
    }
    STAGE_W(W2, 0)
    __syncthreads();

    f32x4 acc2[4][2];
#pragma unroll
    for (int r = 0; r < 4; ++r)
#pragma unroll
        for (int t = 0; t < 2; ++t) acc2[r][t] = (f32x4){0.f, 0.f, 0.f, 0.f};

#define CONV2_CHUNK(h)                                                        \
    {                                                                         \
        int icg = (h) * 4 + lg;                                               \
        _Pragma("unroll")                                                     \
        for (int dx = 0; dx < 3; ++dx) {                                      \
            half8 Bf[6];                                                      \
            _Pragma("unroll")                                                 \
            for (int d = 0; d < 6; ++d) {                                     \
                int pl = (r0 + d) * 18 + lx + dx;                             \
                Bf[d] = *(const half8*)&sMid[pl * 64 + ((icg ^ (pl & 7)) << 3)]; \
            }                                                                 \
            _Pragma("unroll")                                                 \
            for (int dy = 0; dy < 3; ++dy) {                                  \
                int tap = dy * 3 + dx;                                        \
                half8 Af[2];                                                  \
                _Pragma("unroll")                                             \
                for (int t = 0; t < 2; ++t) {                                 \
                    int oc = hh * 32 + t * 16 + lx;                           \
                    Af[t] = *(const half8*)&sW[(tap * 64 + oc) * 32 + ((lg ^ (lx & 3)) << 3)]; \
                }                                                             \
                _Pragma("unroll")                                             \
                for (int r = 0; r < 4; ++r)                                   \
                    _Pragma("unroll")                                         \
                    for (int t = 0; t < 2; ++t)                               \
                        acc2[r][t] = __builtin_amdgcn_mfma_f32_16x16x32_f16(  \
                            Af[t], Bf[r + dy], acc2[r][t], 0, 0, 0);          \
            }                                                                 \
        }                                                                     \
    }

    // ---- P5: conv2 ic-half 0 ----
    CONV2_CHUNK(0)
    __syncthreads();
    // ---- P6: restage sW <- W2 ic-half 1 ----
    STAGE_W(W2, 1)
    __syncthreads();
    // ---- P7: conv2 ic-half 1 + epilogue (bias + reg-residual) ----
    CONV2_CHUNK(1)
    {
        int gx0 = bx * 16 + lx;
#pragma unroll
        for (int r = 0; r < 4; ++r) {
            int y = by * 8 + r0 + r;
#pragma unroll
            for (int t = 0; t < 2; ++t) {
                int oc0 = hh * 32 + t * 16 + lg * 4;
                f32x4 bv = *(const f32x4*)&b2[oc0];
                size_t gi = ((((size_t)n * 16 + (oc0 >> 2)) * HH + y) * WW + gx0) * 4;
                half4_t o;
#pragma unroll
                for (int q = 0; q < 4; ++q)
                    o[q] = (_Float16)(acc2[r][t][q] + bv[q] + (float)rs[r][t][q]);
                *(half4_t*)&out[gi] = o;
            }
        }
    }
#undef STAGE_W
#undef CONV1_CHUNK
#undef CONV2_CHUNK
}

// ---------------------------------------------------------------------------
// MFMA conv, IC=64, 512 threads / 8 waves, tile 16x16 px. oc-loop in chunks
// of 32 with the weight chunk STAGED IN LDS (xor-swizzled). Waves = 8
// row-groups of 2 rows; each wave computes 2 rows x 16 px x 32 oc.
// ---------------------------------------------------------------------------
template<bool RES, bool NT>
__global__ __launch_bounds__(512, 2)
void mconv_k(const _Float16* __restrict__ in, const _Float16* __restrict__ Wt,
             const float* __restrict__ bias, const _Float16* __restrict__ resid,
             _Float16* __restrict__ out, int OCp, int OCr, int C4) {
    __shared__ __align__(16) _Float16 sIn[18 * 18 * 64];  // 41.5 KB
    __shared__ __align__(16) _Float16 sW[9 * 32 * 64];    // 36.9 KB

    int tid = threadIdx.x;
    int n = blockIdx.z, bx = blockIdx.x, by = blockIdx.y;

    for (int i = tid; i < 2592; i += 512) {
        int icg = i / 324, pl = i - icg * 324;
        int py = pl / 18, px = pl - py * 18;
        int gy = by * 16 + py - 1, gx = bx * 16 + px - 1;
        half8 v = {0, 0, 0, 0, 0, 0, 0, 0};
        if ((unsigned)gy < (unsigned)HH && (unsigned)gx < (unsigned)WW) {
            size_t base = ((((size_t)n * 16 + icg * 2) * HH + gy) * WW + gx) * 4;
            half4_t a = *(const half4_t*)&in[base];
            half4_t c = *(const half4_t*)&in[base + (size_t)HH * WW * 4];
            v[0] = a[0]; v[1] = a[1]; v[2] = a[2]; v[3] = a[3];
            v[4] = c[0]; v[5] = c[1]; v[6] = c[2]; v[7] = c[3];
        }
        *(half8*)&sIn[pl * 64 + ((icg ^ (pl & 7)) << 3)] = v;
    }
    __syncthreads();

    int wv = tid >> 6, lane = tid & 63;
    int lx = lane & 15, lg = lane >> 4;
    int r0 = wv * 2;
    int gx0 = bx * 16 + lx;

    for (int ocb = 0; ocb < OCp; ocb += 32) {
        __syncthreads();  // previous iter's sW readers done
        for (int i = tid; i < 2304; i += 512) {
            int tap = i >> 8, oc = (i >> 3) & 31, icg = i & 7;
            half8 v = *(const half8*)&Wt[((size_t)(tap * OCp + ocb + oc)) * 64 + icg * 8];
            *(half8*)&sW[(tap * 32 + oc) * 64 + ((icg ^ (oc & 7)) << 3)] = v;
        }
        __syncthreads();

        f32x4 acc[2][2];
#pragma unroll
        for (int r = 0; r < 2; ++r)
#pragma unroll
            for (int t = 0; t < 2; ++t) acc[r][t] = (f32x4){0.f, 0.f, 0.f, 0.f};

#pragma unroll
        for (int icstep = 0; icstep < 2; ++icstep) {
            int icoff = icstep * 32 + lg * 8;
            int icg   = icoff >> 3;
#pragma unroll
            for (int dx = 0; dx < 3; ++dx) {
                half8 Bf[4];
#pragma unroll
                for (int d = 0; d < 4; ++d) {
                    int pl = (r0 + d) * 18 + lx + dx;
                    Bf[d] = *(const half8*)&sIn[pl * 64 + ((icg ^ (pl & 7)) << 3)];
                }
#pragma unroll
                for (int dy = 0; dy < 3; ++dy) {
                    int tap = dy * 3 + dx;
                    half8 Af[2];
#pragma unroll
                    for (int t = 0; t < 2; ++t) {
                        int oc = t * 16 + lx;
                        Af[t] = *(const half8*)&sW[(tap * 32 + oc) * 64 + ((icg ^ (oc & 7)) << 3)];
                    }
#pragma unroll
                    for (int r = 0; r < 2; ++r)
#pragma unroll
                        for (int t = 0; t < 2; ++t)
                            acc[r][t] = __builtin_amdgcn_mfma_f32_16x16x32_f16(
                                Af[t], Bf[r + dy], acc[r][t], 0, 0, 0);
                }
            }
        }
#pragma unroll
        for (int r = 0; r < 2; ++r) {
            int y = by * 16 + r0 + r;
#pragma unroll
            for (int t = 0; t < 2; ++t) {
                int oc0 = ocb + t * 16 + lg * 4;
                if (oc0 >= OCr) continue;
                f32x4 bv = *(const f32x4*)&bias[oc0];
                size_t gi = ((((size_t)n * C4 + (oc0 >> 2)) * HH + y) * WW + gx0) * 4;
                float vv[4];
#pragma unroll
                for (int q = 0; q < 4; ++q) vv[q] = acc[r][t][q] + bv[q];
                if (RES) {
                    half4_t rg = *(const half4_t*)&resid[gi];
#pragma unroll
                    for (int q = 0; q < 4; ++q) vv[q] += (float)rg[q];
                }
                half4_t o;
#pragma unroll
                for (int q = 0; q < 4; ++q) o[q] = (_Float16)vv[q];
                if (NT) __builtin_nontemporal_store(o, (half4_t*)&out[gi]);
                else    *(half4_t*)&out[gi] = o;
            }
        }
    }
}

// ---------------------------------------------------------------------------
// Out conv 100->3 over pixel-shuffled super output, r8: LDS-staged granule
// tiles (10-ic chunks, 18x18 granules = 25.9 KB) replace the 900 scalar
// global gathers per thread. Thread = 1 granule = 2x2 output quad. Mean add.
// ---------------------------------------------------------------------------
__global__ __launch_bounds__(256)
void out_k(const _Float16* __restrict__ S, const float* __restrict__ w,
           const float* __restrict__ b, float* __restrict__ out) {
    __shared__ __align__(8) _Float16 sG[10 * 18 * 18 * 4];  // 25.9 KB
    int n = blockIdx.z;
    int tid = threadIdx.x;
    int ty = tid >> 4, tx = tid & 15;
    int a  = blockIdx.y * 16 + ty;
    int bc = blockIdx.x * 16 + tx;
    float acc[3][2][2];
#pragma unroll
    for (int c = 0; c < 3; ++c)
#pragma unroll
        for (int oy = 0; oy < 2; ++oy)
#pragma unroll
            for (int ox = 0; ox < 2; ++ox) acc[c][oy][ox] = 0.f;

    for (int ch = 0; ch < 10; ++ch) {
        __syncthreads();
        for (int i = tid; i < 3240; i += 256) {
            int ic = i / 324, pl = i - ic * 324;
            int py = pl / 18, px = pl - py * 18;
            int Y = blockIdx.y * 16 + py - 1, X = blockIdx.x * 16 + px - 1;
            half4_t v = {0, 0, 0, 0};
            if ((unsigned)Y < 128u && (unsigned)X < 128u)
                v = *(const half4_t*)&S[((((size_t)n * 100 + ch * 10 + ic) * 128 + Y) * 128 + X) * 4];
            *(half4_t*)&sG[(ic * 324 + pl) * 4] = v;
        }
        __syncthreads();
        for (int ic = 0; ic < 10; ++ic) {
            float g[3][3][4];
#pragma unroll
            for (int yi = 0; yi < 3; ++yi)
#pragma unroll
                for (int xi = 0; xi < 3; ++xi) {
                    half4_t hv = *(const half4_t*)&sG[((ic * 18 + ty + yi) * 18 + tx + xi) * 4];
#pragma unroll
                    for (int s = 0; s < 4; ++s) g[yi][xi][s] = (float)hv[s];
                }
            int icg = ch * 10 + ic;
#pragma unroll
            for (int oy = 0; oy < 2; ++oy)
#pragma unroll
                for (int ox = 0; ox < 2; ++ox)
#pragma unroll
                    for (int dy = 0; dy < 3; ++dy)
#pragma unroll
                        for (int dx = 0; dx < 3; ++dx) {
                            const int ey = oy + dy - 1, ex = ox + dx - 1;
                            const int yi = (ey >> 1) + 1, xi = (ex >> 1) + 1;
                            const int sub = (ey & 1) * 2 + (ex & 1);
                            float v = g[yi][xi][sub];
#pragma unroll
                            for (int c = 0; c < 3; ++c)
                                acc[c][oy][ox] = fmaf(v, w[(c * 100 + icg) * 9 + dy * 3 + dx],
                                                      acc[c][oy][ox]);
                        }
        }
    }
    const float madd[3] = {255.0f * 0.4488f, 255.0f * 0.4371f, 255.0f * 0.4040f};
#pragma unroll
    for (int c = 0; c < 3; ++c)
#pragma unroll
        for (int oy = 0; oy < 2; ++oy)
#pragma unroll
            for (int ox = 0; ox < 2; ++ox)
                out[(((size_t)n * 3 + c) * 256 + 2 * a + oy) * 256 + 2 * bc + ox] =
                    acc[c][oy][ox] + b[c] + madd[c];
}

// ---------------------------------------------------------------------------
extern "C" void kernel_launch(void* const* d_in, const int* in_sizes, int n_in,
                              void* d_out, int out_size, void* d_ws, size_t ws_size,
                              hipStream_t stream) {
    const float* x       = (const float*)d_in[0];
    const float* head_w  = (const float*)d_in[1];
    const float* head_b  = (const float*)d_in[2];
    const float* rb_w1   = (const float*)d_in[3];
    const float* rb_b1   = (const float*)d_in[4];
    const float* rb_w2   = (const float*)d_in[5];
    const float* rb_b2   = (const float*)d_in[6];
    const float* body_w  = (const float*)d_in[7];
    const float* body_b  = (const float*)d_in[8];
    const float* super_w = (const float*)d_in[9];
    const float* super_b = (const float*)d_in[10];
    const float* out_w   = (const float*)d_in[11];
    const float* out_b   = (const float*)d_in[12];
    float* out = (float*)d_out;

    const size_t ACT = (size_t)16777216;  // bytes per f16 activation buffer
    char* wsb = (char*)d_ws;
    _Float16* Tb = (_Float16*)wsb;                      // ping / body-out / super-in
    _Float16* Hb = (_Float16*)(wsb + ACT);              // head out (kept for body skip)
    _Float16* Cb = (_Float16*)(wsb + 2 * ACT);          // pong
    _Float16* Sb = (_Float16*)(wsb + ACT);              // super out (Hb/Cb dead then)
    _Float16* Wt = (_Float16*)(wsb + ACT + 104857600);

    // 0) weight transform
    wxform_k<<<dim3(1440), 256, 0, stream>>>(rb_w1, rb_w2, body_w, super_w, Wt);

    // 1) head
    head_k<<<dim3(8, 8, 8), 256, 0, stream>>>(x, head_w, head_b, Hb);

    const _Float16* Wt_bod = Wt + (size_t)32 * 36864;
    const _Float16* Wt_sup = Wt + (size_t)33 * 36864;

    // 2) fused resblocks (ping-pong Tb/Cb; Hb preserved)
    const _Float16* cur = Hb;
    for (int i = 0; i < 16; ++i) {
        _Float16* dst = (i & 1) ? Cb : Tb;
        frb_k<<<dim3(8, 16, 8), 256, 0, stream>>>(
            cur, Wt + (size_t)i * 36864, Wt + (size_t)(16 + i) * 36864,
            rb_b1 + i * 64, rb_b2 + i * 64, dst);
        cur = dst;
    }
    // cur == Cb after rb15
    // 3) body conv + head skip -> Tb
    mconv_k<true, false><<<dim3(8, 8, 8), 512, 0, stream>>>(
        Cb, Wt_bod, body_b, Hb, Tb, 64, 64, 16);
    // 4) super conv 64->400 (padded 448) -> Sb, nontemporal stores
    mconv_k<false, true><<<dim3(8, 8, 8), 512, 0, stream>>>(
        Tb, Wt_sup, super_b, nullptr, Sb, 448, 400, 100);
    // 5) out conv over pixel-shuffled granules + mean add
    out_k<<<dim3(8, 8, 8), 256, 0, stream>>>(Sb, out_w, out_b, out);
}